// Round 10
// baseline (481.825 us; speedup 1.0000x reference)
//
#include <hip/hip_runtime.h>
#include <hip/hip_fp16.h>

static constexpr int N_NODES = 500000;
static constexpr int N_EDGES = 16000000;

typedef int  iv4 __attribute__((ext_vector_type(4)));
typedef unsigned int uv4 __attribute__((ext_vector_type(4)));

// ---------- fast-path geometry ----------
static constexpr int BUCKET_SHIFT = 9;                 // 512 nodes / bucket
static constexpr int BUCKET_NODES = 1 << BUCKET_SHIFT; // 512
static constexpr int NB = (N_NODES + BUCKET_NODES - 1) >> BUCKET_SHIFT; // 977
static constexpr int NBUCK = 1024;                     // padded pow2 for LDS arrays
static constexpr int CAP = 17920;                      // per-bucket capacity (mean 16384, +12 sigma)
static constexpr int CHUNK = 10000;                    // edges per bin-block (staged = 40 KB)
static constexpr int BLOCKS_A = N_EDGES / CHUNK;       // 1600
static constexpr int FILL_STRIDE = 16;                 // one counter per 64B line
static constexpr int HALF_SHIFT = 18;                  // src halves: [0,262144), [262144,500000)

// ws layout (bytes) — total <= 76,224,512 (proven available)
static constexpr size_t REC_OFF  = 0;                                  // u32[NB*CAP] = 70,031,360
static constexpr size_t AGG_OFF  = (size_t)NB * CAP * 4;               // f32[NB*512*3] = 6,002,688
static constexpr size_t FILL_OFF = AGG_OFF + (size_t)NB * BUCKET_NODES * 3 * 4; // 65,536
static constexpr size_t SUMS_OFF = FILL_OFF + 65536;                   // double[4]
static constexpr size_t WS_NEEDED = SUMS_OFF + 32;                     // 76,099,616

__device__ __forceinline__ int imin(int a, int b) { return a < b ? a : b; }

// =====================================================================
// FAST PATH
// =====================================================================

// zero bucketFill and sums (gather table is now x itself — no xm precompute)
__global__ void prep_kernel(int* __restrict__ bucketFill,
                            double* __restrict__ sums) {
    int i = blockIdx.x * blockDim.x + threadIdx.x;
    if (i < NBUCK) bucketFill[i * FILL_STRIDE] = 0;
    if (i == 0) { sums[0] = 0.0; sums[1] = 0.0; sums[2] = 0.0; }
}

// Partition edges into buckets of 512 dst nodes. 512 threads.
__global__ __launch_bounds__(512) void bin_kernel(const int* __restrict__ edge_src,
                                                  const int* __restrict__ edge_dst,
                                                  int* __restrict__ bucketFill,
                                                  unsigned int* __restrict__ records) {
    __shared__ int cnt[NBUCK];                 // 4 KB: histogram, then cursor
    __shared__ unsigned short start[NBUCK];    // 2 KB
    __shared__ unsigned short gbase[NBUCK];    // 2 KB
    __shared__ int part[256];                  // 1 KB
    __shared__ unsigned int staged[CHUNK];     // 40 KB

    const int t = threadIdx.x;
    const long e0 = (long)blockIdx.x * CHUNK;
    const iv4* __restrict__ dst4 = reinterpret_cast<const iv4*>(edge_dst + e0);
    const iv4* __restrict__ src4 = reinterpret_cast<const iv4*>(edge_src + e0);

    for (int b = t; b < NBUCK; b += 512) cnt[b] = 0;
    __syncthreads();

    // pass 1: histogram of dst buckets
    for (int i = t; i < CHUNK / 4; i += 512) {
        iv4 d = __builtin_nontemporal_load(dst4 + i);
        atomicAdd(&cnt[d.x >> BUCKET_SHIFT], 1);
        atomicAdd(&cnt[d.y >> BUCKET_SHIFT], 1);
        atomicAdd(&cnt[d.z >> BUCKET_SHIFT], 1);
        atomicAdd(&cnt[d.w >> BUCKET_SHIFT], 1);
    }
    __syncthreads();

    // exclusive scan of cnt[0..1023] -> start[] (threads 0..255 drive)
    int a0 = 0, a1 = 0, a2 = 0, a3 = 0, tsum = 0;
    if (t < 256) {
        a0 = cnt[4 * t + 0]; a1 = cnt[4 * t + 1]; a2 = cnt[4 * t + 2]; a3 = cnt[4 * t + 3];
        tsum = a0 + a1 + a2 + a3;
        part[t] = tsum;
    }
    __syncthreads();
    for (int off = 1; off < 256; off <<= 1) {
        int u = 0, v = 0;
        if (t < 256) { u = part[t]; v = (t >= off) ? part[t - off] : 0; }
        __syncthreads();
        if (t < 256) part[t] = u + v;
        __syncthreads();
    }
    if (t < 256) {
        int texcl = part[t] - tsum;
        start[4 * t + 0] = (unsigned short)texcl;
        start[4 * t + 1] = (unsigned short)(texcl + a0);
        start[4 * t + 2] = (unsigned short)(texcl + a0 + a1);
        start[4 * t + 3] = (unsigned short)(texcl + a0 + a1 + a2);
    }
    __syncthreads();

    // global reservation (rotated, padded counters); then cursor = start
    for (int j = t; j < NBUCK; j += 512) {
        int b = (j + blockIdx.x * 7) & (NBUCK - 1);
        int c = cnt[b];
        gbase[b] = (unsigned short)((c > 0) ? atomicAdd(&bucketFill[b * FILL_STRIDE], c) : 0);
    }
    __syncthreads();
    for (int b = t; b < NBUCK; b += 512) cnt[b] = (int)start[b];
    __syncthreads();

    // pass 2: stage records grouped by bucket
    for (int i = t; i < CHUNK / 4; i += 512) {
        iv4 d = __builtin_nontemporal_load(dst4 + i);
        iv4 s = __builtin_nontemporal_load(src4 + i);
        int dd[4] = { d.x, d.y, d.z, d.w };
        int ss[4] = { s.x, s.y, s.z, s.w };
        #pragma unroll
        for (int k = 0; k < 4; ++k) {
            int b = dd[k] >> BUCKET_SHIFT;
            int r = atomicAdd(&cnt[b], 1);
            staged[r] = ((unsigned int)(dd[k] & (BUCKET_NODES - 1)) << 20) | (unsigned int)ss[k];
        }
    }
    __syncthreads();

    // pass 3: wave-per-bucket copy (8 waves) — run-contiguous nt global write
    const int wv = t >> 6, ln = t & 63;
    for (int b = wv; b < NBUCK; b += 8) {
        int s0 = (int)start[b];
        int c  = cnt[b] - s0;
        int g  = (int)gbase[b];
        for (int i = ln; i < c; i += 64) {
            int pos = g + i;
            if (pos < CAP)
                __builtin_nontemporal_store(staged[s0 + i], &records[(size_t)b * CAP + pos]);
        }
    }
}

// One block (512 thr) per bucket; TWO LAUNCHES (HALF=0,1). Each launch
// gathers only from a ~3MB slice of x (L2-resident per XCD). Agg carried
// in global between launches via plain store/load. Exploits linearity:
// sum_j x_j @ M == (sum_j x_j) @ M, so we aggregate raw x and apply M once.
template <int HALF>
__global__ __launch_bounds__(512) void bucket_kernel(const unsigned int* __restrict__ records,
                                                     const int* __restrict__ bucketFill,
                                                     float* __restrict__ aggG,
                                                     const float* __restrict__ x,
                                                     const float* __restrict__ W,
                                                     const float* __restrict__ M,
                                                     double* __restrict__ sums) {
    __shared__ float aggL[BUCKET_NODES * 3];   // 6 KB
    __shared__ float stage[8][4 * 192];        // 24 KB: per-wave, 4 regions x 768B
    __shared__ float partw[8][3];

    const int b = blockIdx.x;
    const int t = threadIdx.x;
    const int wv = t >> 6, ln = t & 63;

    if (HALF == 0) {
        for (int i = t; i < BUCKET_NODES * 3; i += 512) aggL[i] = 0.0f;
    } else {
        for (int i = t; i < BUCKET_NODES * 3; i += 512)
            aggL[i] = aggG[(size_t)b * (BUCKET_NODES * 3) + i];
    }
    __syncthreads();

    int cnt = bucketFill[b * FILL_STRIDE];
    if (cnt > CAP) cnt = CAP;
    const unsigned int* __restrict__ rec = records + (size_t)b * CAP;

    // per-wave contiguous slice
    int per = (cnt + 7) >> 3;
    int s0 = wv * per;
    int s1 = imin(s0 + per, cnt);
    int len = s1 - s0;
    float* wstage = &stage[wv][0];

    if (len > 0) {
        int rounds = (len + 255) >> 8;
        for (int r = 0; r < rounds; ++r) {
            int base = s0 + (r << 8);
            // (a) coalesced nt record loads (clamped at slice end)
            unsigned int rr[4];
            bool pk[4];
            #pragma unroll
            for (int k = 0; k < 4; ++k) {
                int idx = base + (k << 6) + ln;
                rr[k] = __builtin_nontemporal_load(rec + imin(idx, s1 - 1));
                pk[k] = (idx < s1) && (((rr[k] & 0xFFFFFu) >> HALF_SHIFT) == HALF);
            }
            // (b) previous round's stage reads must complete before DMA overwrites
            asm volatile("s_waitcnt lgkmcnt(0)" ::: "memory");
            __builtin_amdgcn_sched_barrier(0);
            #pragma unroll
            for (int k = 0; k < 4; ++k) {
                if (pk[k]) {
                    const float* ga = x + (size_t)(rr[k] & 0xFFFFFu) * 3;
                    __builtin_amdgcn_global_load_lds(
                        (const __attribute__((address_space(1))) void*)ga,
                        (__attribute__((address_space(3))) void*)(wstage + k * 192),
                        12, 0, 0);
                }
            }
            asm volatile("s_waitcnt vmcnt(0)" ::: "memory");
            __builtin_amdgcn_sched_barrier(0);
            // (c) accumulate from stage into LDS agg
            #pragma unroll
            for (int k = 0; k < 4; ++k) {
                if (pk[k]) {
                    int dl = (int)(rr[k] >> 20);
                    int sbase = (k * 64 + ln) * 3;
                    atomicAdd(&aggL[dl * 3 + 0], wstage[sbase + 0]);
                    atomicAdd(&aggL[dl * 3 + 1], wstage[sbase + 1]);
                    atomicAdd(&aggL[dl * 3 + 2], wstage[sbase + 2]);
                }
            }
        }
    }
    __syncthreads();

    if (HALF == 0) {
        // spill partial agg to global (coalesced)
        for (int i = t; i < BUCKET_NODES * 3; i += 512)
            aggG[(size_t)b * (BUCKET_NODES * 3) + i] = aggL[i];
        return;
    }

    // final epilogue: h = relu(x@W + agg@M); one node per thread
    float s0f = 0.0f, s1f = 0.0f, s2f = 0.0f;
    {
        int node = (b << BUCKET_SHIFT) + t;
        if (node < N_NODES) {
            float w00 = W[0], w01 = W[1], w02 = W[2];
            float w10 = W[3], w11 = W[4], w12 = W[5];
            float w20 = W[6], w21 = W[7], w22 = W[8];
            float m00 = M[0], m01 = M[1], m02 = M[2];
            float m10 = M[3], m11 = M[4], m12 = M[5];
            float m20 = M[6], m21 = M[7], m22 = M[8];
            float x0 = x[node * 3 + 0], x1 = x[node * 3 + 1], x2 = x[node * 3 + 2];
            float a0 = aggL[t * 3 + 0], a1 = aggL[t * 3 + 1], a2 = aggL[t * 3 + 2];
            float t0 = x0 * w00 + x1 * w10 + x2 * w20 + a0 * m00 + a1 * m10 + a2 * m20;
            float t1 = x0 * w01 + x1 * w11 + x2 * w21 + a0 * m01 + a1 * m11 + a2 * m21;
            float t2 = x0 * w02 + x1 * w12 + x2 * w22 + a0 * m02 + a1 * m12 + a2 * m22;
            s0f = t0 > 0.0f ? t0 : 0.0f;
            s1f = t1 > 0.0f ? t1 : 0.0f;
            s2f = t2 > 0.0f ? t2 : 0.0f;
        }
    }

    #pragma unroll
    for (int off = 32; off > 0; off >>= 1) {
        s0f += __shfl_down(s0f, off);
        s1f += __shfl_down(s1f, off);
        s2f += __shfl_down(s2f, off);
    }
    if (ln == 0) { partw[wv][0] = s0f; partw[wv][1] = s1f; partw[wv][2] = s2f; }
    __syncthreads();
    if (t == 0) {
        double d0 = 0.0, d1 = 0.0, d2 = 0.0;
        #pragma unroll
        for (int w = 0; w < 8; ++w) {
            d0 += (double)partw[w][0];
            d1 += (double)partw[w][1];
            d2 += (double)partw[w][2];
        }
        atomicAdd(&sums[0], d0);
        atomicAdd(&sums[1], d1);
        atomicAdd(&sums[2], d2);
    }
}

__global__ void softmax_kernel(const double* __restrict__ sums,
                               float* __restrict__ out) {
    if (blockIdx.x == 0 && threadIdx.x == 0) {
        double s0 = sums[0], s1 = sums[1], s2 = sums[2];
        double m = fmax(s0, fmax(s1, s2));
        double e0 = exp(s0 - m), e1 = exp(s1 - m), e2 = exp(s2 - m);
        double tt = e0 + e1 + e2;
        out[0] = (float)(e0 / tt);
        out[1] = (float)(e1 / tt);
        out[2] = (float)(e2 / tt);
    }
}

// =====================================================================
// FALLBACK PATH (proven R1 code) — used if ws_size < WS_NEEDED
// =====================================================================

__global__ void fb_precompute(const float* __restrict__ x, const float* __restrict__ M,
                              float* __restrict__ xm, float* __restrict__ agg,
                              double* __restrict__ sums) {
    int i = blockIdx.x * blockDim.x + threadIdx.x;
    if (i == 0) { sums[0] = 0.0; sums[1] = 0.0; sums[2] = 0.0; }
    if (i < N_NODES) {
        float m00 = M[0], m01 = M[1], m02 = M[2];
        float m10 = M[3], m11 = M[4], m12 = M[5];
        float m20 = M[6], m21 = M[7], m22 = M[8];
        float x0 = x[i * 3 + 0], x1 = x[i * 3 + 1], x2 = x[i * 3 + 2];
        xm[i * 3 + 0] = x0 * m00 + x1 * m10 + x2 * m20;
        xm[i * 3 + 1] = x0 * m01 + x1 * m11 + x2 * m21;
        xm[i * 3 + 2] = x0 * m02 + x1 * m12 + x2 * m22;
        agg[i * 3 + 0] = 0.0f; agg[i * 3 + 1] = 0.0f; agg[i * 3 + 2] = 0.0f;
    }
}

__global__ void fb_scatter(const int* __restrict__ edge_src, const int* __restrict__ edge_dst,
                           const float* __restrict__ xm, float* __restrict__ agg) {
    const int tid = blockIdx.x * blockDim.x + threadIdx.x;
    const int stride = gridDim.x * blockDim.x;
    const int4* src4 = reinterpret_cast<const int4*>(edge_src);
    const int4* dst4 = reinterpret_cast<const int4*>(edge_dst);
    const int n4 = N_EDGES / 4;
    for (int e = tid; e < n4; e += stride) {
        int4 s = src4[e]; int4 d = dst4[e];
        int ss[4] = { s.x, s.y, s.z, s.w };
        int dd[4] = { d.x, d.y, d.z, d.w };
        float v[4][3];
        #pragma unroll
        for (int k = 0; k < 4; ++k) {
            int bb = ss[k] * 3;
            v[k][0] = xm[bb + 0]; v[k][1] = xm[bb + 1]; v[k][2] = xm[bb + 2];
        }
        #pragma unroll
        for (int k = 0; k < 4; ++k) {
            int bb = dd[k] * 3;
            atomicAdd(&agg[bb + 0], v[k][0]);
            atomicAdd(&agg[bb + 1], v[k][1]);
            atomicAdd(&agg[bb + 2], v[k][2]);
        }
    }
}

__global__ void fb_reduce(const float* __restrict__ x, const float* __restrict__ W,
                          const float* __restrict__ agg, double* __restrict__ sums) {
    __shared__ float part[4][3];
    int i = blockIdx.x * blockDim.x + threadIdx.x;
    float h0 = 0.0f, h1 = 0.0f, h2 = 0.0f;
    if (i < N_NODES) {
        float w00 = W[0], w01 = W[1], w02 = W[2];
        float w10 = W[3], w11 = W[4], w12 = W[5];
        float w20 = W[6], w21 = W[7], w22 = W[8];
        float x0 = x[i * 3 + 0], x1 = x[i * 3 + 1], x2 = x[i * 3 + 2];
        float t0 = x0 * w00 + x1 * w10 + x2 * w20 + agg[i * 3 + 0];
        float t1 = x0 * w01 + x1 * w11 + x2 * w21 + agg[i * 3 + 1];
        float t2 = x0 * w02 + x1 * w12 + x2 * w22 + agg[i * 3 + 2];
        h0 = t0 > 0.0f ? t0 : 0.0f; h1 = t1 > 0.0f ? t1 : 0.0f; h2 = t2 > 0.0f ? t2 : 0.0f;
    }
    #pragma unroll
    for (int off = 32; off > 0; off >>= 1) {
        h0 += __shfl_down(h0, off); h1 += __shfl_down(h1, off); h2 += __shfl_down(h2, off);
    }
    int lane = threadIdx.x & 63, wave = threadIdx.x >> 6;
    if (lane == 0) { part[wave][0] = h0; part[wave][1] = h1; part[wave][2] = h2; }
    __syncthreads();
    if (threadIdx.x == 0) {
        double d0 = 0.0, d1 = 0.0, d2 = 0.0;
        #pragma unroll
        for (int w = 0; w < 4; ++w) {
            d0 += (double)part[w][0]; d1 += (double)part[w][1]; d2 += (double)part[w][2];
        }
        atomicAdd(&sums[0], d0); atomicAdd(&sums[1], d1); atomicAdd(&sums[2], d2);
    }
}

// =====================================================================

extern "C" void kernel_launch(void* const* d_in, const int* in_sizes, int n_in,
                              void* d_out, int out_size, void* d_ws, size_t ws_size,
                              hipStream_t stream) {
    const float* x        = (const float*)d_in[0];
    const float* W        = (const float*)d_in[1];
    const float* M        = (const float*)d_in[2];
    const int*   edge_src = (const int*)d_in[3];
    const int*   edge_dst = (const int*)d_in[4];
    float* out = (float*)d_out;

    char* ws = (char*)d_ws;
    const int nodeBlocks = (N_NODES + 255) / 256;

    if (ws_size >= WS_NEEDED) {
        unsigned int* records    = (unsigned int*)(ws + REC_OFF);
        float*        aggG       = (float*)(ws + AGG_OFF);
        int*          bucketFill = (int*)(ws + FILL_OFF);
        double*       sums       = (double*)(ws + SUMS_OFF);

        prep_kernel<<<4, 256, 0, stream>>>(bucketFill, sums);
        bin_kernel<<<BLOCKS_A, 512, 0, stream>>>(edge_src, edge_dst, bucketFill, records);
        bucket_kernel<0><<<NB, 512, 0, stream>>>(records, bucketFill, aggG, x, W, M, sums);
        bucket_kernel<1><<<NB, 512, 0, stream>>>(records, bucketFill, aggG, x, W, M, sums);
        softmax_kernel<<<1, 1, 0, stream>>>(sums, out);
    } else {
        float*  xm   = (float*)ws;
        float*  agg  = xm + (size_t)N_NODES * 3;
        double* sums = (double*)(agg + (size_t)N_NODES * 3);

        fb_precompute<<<nodeBlocks, 256, 0, stream>>>(x, M, xm, agg, sums);
        fb_scatter<<<2048, 256, 0, stream>>>(edge_src, edge_dst, xm, agg);
        fb_reduce<<<nodeBlocks, 256, 0, stream>>>(x, W, agg, sums);
        softmax_kernel<<<1, 1, 0, stream>>>(sums, out);
    }
}

// Round 13
// 348.153 us; speedup vs baseline: 1.3839x; 1.3839x over previous
//
#include <hip/hip_runtime.h>
#include <hip/hip_fp16.h>

static constexpr int N_NODES = 500000;
static constexpr int N_EDGES = 16000000;

typedef int  iv4 __attribute__((ext_vector_type(4)));
typedef unsigned int uv4 __attribute__((ext_vector_type(4)));

// ---------- fast-path geometry (R5 proven) ----------
static constexpr int BUCKET_SHIFT = 9;                 // 512 nodes / bucket
static constexpr int BUCKET_NODES = 1 << BUCKET_SHIFT; // 512
static constexpr int NB = (N_NODES + BUCKET_NODES - 1) >> BUCKET_SHIFT; // 977
static constexpr int NBUCK = 1024;                     // padded pow2 for LDS arrays
static constexpr int CAP = 18432;                      // per-bucket capacity (mean 16378)
static constexpr int CHUNK = 10000;                    // edges per bin-block (staged = 40 KB)
static constexpr int BLOCKS_A = N_EDGES / CHUNK;       // 1600

// ws layout (bytes) — identical to R5 (proven)
static constexpr size_t XMP_OFF  = 0;                          // ushort4[N_NODES] = 4,000,000
static constexpr size_t SUMS_OFF = 4000000;                    // double[4]
static constexpr size_t FILL_OFF = 4000064;                    // int[1024]
static constexpr size_t REC_OFF  = 4194304;                    // u32[NB*CAP] = 72,030,208
static constexpr size_t WS_NEEDED = REC_OFF + (size_t)NB * CAP * 4;  // 76,224,512

// LDS packed-f16 atomic add: ds_pk_add_f16 (gfx90a+, CDNA4)
__device__ __forceinline__ void lds_pk_add_f16(unsigned int* gptr, unsigned int val) {
    unsigned addr = (unsigned)(size_t)(__attribute__((address_space(3))) unsigned int*)gptr;
    asm volatile("ds_pk_add_f16 %0, %1" :: "v"(addr), "v"(val) : "memory");
}

// =====================================================================
// FAST PATH
// =====================================================================

// xm(f16x4) = x @ M ; zero bucketFill and sums
__global__ void prep_kernel(const float* __restrict__ x,
                            const float* __restrict__ M,
                            ushort4* __restrict__ xmp,
                            int* __restrict__ bucketFill,
                            double* __restrict__ sums) {
    int i = blockIdx.x * blockDim.x + threadIdx.x;
    if (i < NBUCK) bucketFill[i] = 0;
    if (i == 0) { sums[0] = 0.0; sums[1] = 0.0; sums[2] = 0.0; }
    if (i < N_NODES) {
        float m00 = M[0], m01 = M[1], m02 = M[2];
        float m10 = M[3], m11 = M[4], m12 = M[5];
        float m20 = M[6], m21 = M[7], m22 = M[8];
        float x0 = x[i * 3 + 0], x1 = x[i * 3 + 1], x2 = x[i * 3 + 2];
        float v0 = x0 * m00 + x1 * m10 + x2 * m20;
        float v1 = x0 * m01 + x1 * m11 + x2 * m21;
        float v2 = x0 * m02 + x1 * m12 + x2 * m22;
        ushort4 u;
        u.x = __half_as_ushort(__float2half_rn(v0));
        u.y = __half_as_ushort(__float2half_rn(v1));
        u.z = __half_as_ushort(__float2half_rn(v2));
        u.w = 0;
        xmp[i] = u;
    }
}

// Partition edges into buckets of 512 dst nodes. 512 threads. (R5 verbatim)
__global__ __launch_bounds__(512) void bin_kernel(const int* __restrict__ edge_src,
                                                  const int* __restrict__ edge_dst,
                                                  int* __restrict__ bucketFill,
                                                  unsigned int* __restrict__ records) {
    __shared__ int cnt[NBUCK];                 // 4 KB: histogram, then cursor
    __shared__ unsigned short start[NBUCK];    // 2 KB
    __shared__ unsigned short gbase[NBUCK];    // 2 KB
    __shared__ int part[256];                  // 1 KB
    __shared__ unsigned int staged[CHUNK];     // 40 KB

    const int t = threadIdx.x;
    const long e0 = (long)blockIdx.x * CHUNK;
    const iv4* __restrict__ dst4 = reinterpret_cast<const iv4*>(edge_dst + e0);
    const iv4* __restrict__ src4 = reinterpret_cast<const iv4*>(edge_src + e0);

    for (int b = t; b < NBUCK; b += 512) cnt[b] = 0;
    __syncthreads();

    // pass 1: histogram of dst buckets (nt int4 loads)
    for (int i = t; i < CHUNK / 4; i += 512) {
        iv4 d = __builtin_nontemporal_load(dst4 + i);
        atomicAdd(&cnt[d.x >> BUCKET_SHIFT], 1);
        atomicAdd(&cnt[d.y >> BUCKET_SHIFT], 1);
        atomicAdd(&cnt[d.z >> BUCKET_SHIFT], 1);
        atomicAdd(&cnt[d.w >> BUCKET_SHIFT], 1);
    }
    __syncthreads();

    // exclusive scan of cnt[0..1023] -> start[] (threads 0..255 drive)
    int a0 = 0, a1 = 0, a2 = 0, a3 = 0, tsum = 0;
    if (t < 256) {
        a0 = cnt[4 * t + 0]; a1 = cnt[4 * t + 1]; a2 = cnt[4 * t + 2]; a3 = cnt[4 * t + 3];
        tsum = a0 + a1 + a2 + a3;
        part[t] = tsum;
    }
    __syncthreads();
    for (int off = 1; off < 256; off <<= 1) {
        int u = 0, v = 0;
        if (t < 256) { u = part[t]; v = (t >= off) ? part[t - off] : 0; }
        __syncthreads();
        if (t < 256) part[t] = u + v;
        __syncthreads();
    }
    if (t < 256) {
        int texcl = part[t] - tsum;
        start[4 * t + 0] = (unsigned short)texcl;
        start[4 * t + 1] = (unsigned short)(texcl + a0);
        start[4 * t + 2] = (unsigned short)(texcl + a0 + a1);
        start[4 * t + 3] = (unsigned short)(texcl + a0 + a1 + a2);
    }
    __syncthreads();

    // global reservation (rotated); then cursor = start
    for (int j = t; j < NBUCK; j += 512) {
        int b = (j + blockIdx.x * 7) & (NBUCK - 1);
        int c = cnt[b];
        gbase[b] = (unsigned short)((c > 0) ? atomicAdd(&bucketFill[b], c) : 0);
    }
    __syncthreads();
    for (int b = t; b < NBUCK; b += 512) cnt[b] = (int)start[b];
    __syncthreads();

    // pass 2: stage records grouped by bucket
    for (int i = t; i < CHUNK / 4; i += 512) {
        iv4 d = __builtin_nontemporal_load(dst4 + i);
        iv4 s = __builtin_nontemporal_load(src4 + i);
        int dd[4] = { d.x, d.y, d.z, d.w };
        int ss[4] = { s.x, s.y, s.z, s.w };
        #pragma unroll
        for (int k = 0; k < 4; ++k) {
            int b = dd[k] >> BUCKET_SHIFT;
            int r = atomicAdd(&cnt[b], 1);
            staged[r] = ((unsigned int)(dd[k] & (BUCKET_NODES - 1)) << 20) | (unsigned int)ss[k];
        }
    }
    __syncthreads();

    // pass 3: wave-per-bucket copy (8 waves) — run-contiguous nt global write
    const int wv = t >> 6, ln = t & 63;
    for (int b = wv; b < NBUCK; b += 8) {
        int s0 = (int)start[b];
        int c  = cnt[b] - s0;
        int g  = (int)gbase[b];
        for (int i = ln; i < c; i += 64) {
            int pos = g + i;
            if (pos < CAP)
                __builtin_nontemporal_store(staged[s0 + i], &records[(size_t)b * CAP + pos]);
        }
    }
}

// One block (1024 thr) per bucket: LDS agg, batched f16 gathers, fused epilogue.
// R13 delta vs R5: 2 LDS atomics per record instead of 3 —
//   (v0,v1) accumulated with ONE ds_pk_add_f16 (inline asm), v2 one f32 atomic.
// Tests the LDS-atomic-rate ceiling theory.
__global__ __launch_bounds__(1024) void bucket_kernel(const unsigned int* __restrict__ records,
                                                      const int* __restrict__ bucketFill,
                                                      const ushort4* __restrict__ xmp,
                                                      const float* __restrict__ x,
                                                      const float* __restrict__ W,
                                                      double* __restrict__ sums) {
    __shared__ unsigned int aggH2[BUCKET_NODES];  // 2 KB: packed f16 (v0,v1)
    __shared__ float        aggV2[BUCKET_NODES];  // 2 KB: v2 (f32)
    __shared__ float        partw[16][3];

    const int b = blockIdx.x;
    const int t = threadIdx.x;
    const unsigned long long* __restrict__ xmp8 = (const unsigned long long*)xmp;

    for (int i = t; i < BUCKET_NODES; i += 1024) {
        aggH2[i] = 0u;
        aggV2[i] = 0.0f;
    }
    __syncthreads();

    int cnt = bucketFill[b];
    if (cnt > CAP) cnt = CAP;
    const unsigned int* __restrict__ rec = records + (size_t)b * CAP;
    const uv4* __restrict__ rec4 = reinterpret_cast<const uv4*>(rec);

    const int n4 = cnt >> 2;
    for (int i = t; i < n4; i += 1024) {
        uv4 r = __builtin_nontemporal_load(rec4 + i);
        unsigned int rr[4] = { r.x, r.y, r.z, r.w };
        unsigned long long g[4];
        #pragma unroll
        for (int k = 0; k < 4; ++k) g[k] = xmp8[rr[k] & 0xFFFFFu];
        __builtin_amdgcn_sched_barrier(0);   // keep all 4 gathers in flight
        #pragma unroll
        for (int k = 0; k < 4; ++k) {
            int dl = (int)(rr[k] >> 20);
            unsigned int u01 = (unsigned int)(g[k] & 0xFFFFFFFFull);
            lds_pk_add_f16(&aggH2[dl], u01);
            float v2 = __half2float(__ushort_as_half((unsigned short)((g[k] >> 32) & 0xFFFF)));
            atomicAdd(&aggV2[dl], v2);
        }
    }
    for (int i = (n4 << 2) + t; i < cnt; i += 1024) {
        unsigned int r = rec[i];
        unsigned long long g = xmp8[r & 0xFFFFFu];
        int dl = (int)(r >> 20);
        unsigned int u01 = (unsigned int)(g & 0xFFFFFFFFull);
        lds_pk_add_f16(&aggH2[dl], u01);
        float v2 = __half2float(__ushort_as_half((unsigned short)((g >> 32) & 0xFFFF)));
        atomicAdd(&aggV2[dl], v2);
    }
    __syncthreads();

    // fused epilogue: h = relu(x@W + agg), block partial sum (one node per thread t<512)
    float s0 = 0.0f, s1 = 0.0f, s2 = 0.0f;
    if (t < BUCKET_NODES) {
        int node = (b << BUCKET_SHIFT) + t;
        if (node < N_NODES) {
            float w00 = W[0], w01 = W[1], w02 = W[2];
            float w10 = W[3], w11 = W[4], w12 = W[5];
            float w20 = W[6], w21 = W[7], w22 = W[8];
            float x0 = x[node * 3 + 0], x1 = x[node * 3 + 1], x2 = x[node * 3 + 2];
            unsigned int u = aggH2[t];
            float a0 = __half2float(__ushort_as_half((unsigned short)(u & 0xFFFF)));
            float a1 = __half2float(__ushort_as_half((unsigned short)(u >> 16)));
            float a2f = aggV2[t];
            float t0 = x0 * w00 + x1 * w10 + x2 * w20 + a0;
            float t1 = x0 * w01 + x1 * w11 + x2 * w21 + a1;
            float t2 = x0 * w02 + x1 * w12 + x2 * w22 + a2f;
            s0 = t0 > 0.0f ? t0 : 0.0f;
            s1 = t1 > 0.0f ? t1 : 0.0f;
            s2 = t2 > 0.0f ? t2 : 0.0f;
        }
    }

    #pragma unroll
    for (int off = 32; off > 0; off >>= 1) {
        s0 += __shfl_down(s0, off);
        s1 += __shfl_down(s1, off);
        s2 += __shfl_down(s2, off);
    }
    int lane = t & 63, wave = t >> 6;
    if (lane == 0) { partw[wave][0] = s0; partw[wave][1] = s1; partw[wave][2] = s2; }
    __syncthreads();
    if (t == 0) {
        double d0 = 0.0, d1 = 0.0, d2 = 0.0;
        #pragma unroll
        for (int w = 0; w < 16; ++w) {
            d0 += (double)partw[w][0];
            d1 += (double)partw[w][1];
            d2 += (double)partw[w][2];
        }
        atomicAdd(&sums[0], d0);
        atomicAdd(&sums[1], d1);
        atomicAdd(&sums[2], d2);
    }
}

__global__ void softmax_kernel(const double* __restrict__ sums,
                               float* __restrict__ out) {
    if (blockIdx.x == 0 && threadIdx.x == 0) {
        double s0 = sums[0], s1 = sums[1], s2 = sums[2];
        double m = fmax(s0, fmax(s1, s2));
        double e0 = exp(s0 - m), e1 = exp(s1 - m), e2 = exp(s2 - m);
        double tt = e0 + e1 + e2;
        out[0] = (float)(e0 / tt);
        out[1] = (float)(e1 / tt);
        out[2] = (float)(e2 / tt);
    }
}

// =====================================================================
// FALLBACK PATH (proven R1 code) — used if ws_size < WS_NEEDED
// =====================================================================

__global__ void fb_precompute(const float* __restrict__ x, const float* __restrict__ M,
                              float* __restrict__ xm, float* __restrict__ agg,
                              double* __restrict__ sums) {
    int i = blockIdx.x * blockDim.x + threadIdx.x;
    if (i == 0) { sums[0] = 0.0; sums[1] = 0.0; sums[2] = 0.0; }
    if (i < N_NODES) {
        float m00 = M[0], m01 = M[1], m02 = M[2];
        float m10 = M[3], m11 = M[4], m12 = M[5];
        float m20 = M[6], m21 = M[7], m22 = M[8];
        float x0 = x[i * 3 + 0], x1 = x[i * 3 + 1], x2 = x[i * 3 + 2];
        xm[i * 3 + 0] = x0 * m00 + x1 * m10 + x2 * m20;
        xm[i * 3 + 1] = x0 * m01 + x1 * m11 + x2 * m21;
        xm[i * 3 + 2] = x0 * m02 + x1 * m12 + x2 * m22;
        agg[i * 3 + 0] = 0.0f; agg[i * 3 + 1] = 0.0f; agg[i * 3 + 2] = 0.0f;
    }
}

__global__ void fb_scatter(const int* __restrict__ edge_src, const int* __restrict__ edge_dst,
                           const float* __restrict__ xm, float* __restrict__ agg) {
    const int tid = blockIdx.x * blockDim.x + threadIdx.x;
    const int stride = gridDim.x * blockDim.x;
    const int4* src4 = reinterpret_cast<const int4*>(edge_src);
    const int4* dst4 = reinterpret_cast<const int4*>(edge_dst);
    const int n4 = N_EDGES / 4;
    for (int e = tid; e < n4; e += stride) {
        int4 s = src4[e]; int4 d = dst4[e];
        int ss[4] = { s.x, s.y, s.z, s.w };
        int dd[4] = { d.x, d.y, d.z, d.w };
        float v[4][3];
        #pragma unroll
        for (int k = 0; k < 4; ++k) {
            int bb = ss[k] * 3;
            v[k][0] = xm[bb + 0]; v[k][1] = xm[bb + 1]; v[k][2] = xm[bb + 2];
        }
        #pragma unroll
        for (int k = 0; k < 4; ++k) {
            int bb = dd[k] * 3;
            atomicAdd(&agg[bb + 0], v[k][0]);
            atomicAdd(&agg[bb + 1], v[k][1]);
            atomicAdd(&agg[bb + 2], v[k][2]);
        }
    }
}

__global__ void fb_reduce(const float* __restrict__ x, const float* __restrict__ W,
                          const float* __restrict__ agg, double* __restrict__ sums) {
    __shared__ float part[4][3];
    int i = blockIdx.x * blockDim.x + threadIdx.x;
    float h0 = 0.0f, h1 = 0.0f, h2 = 0.0f;
    if (i < N_NODES) {
        float w00 = W[0], w01 = W[1], w02 = W[2];
        float w10 = W[3], w11 = W[4], w12 = W[5];
        float w20 = W[6], w21 = W[7], w22 = W[8];
        float x0 = x[i * 3 + 0], x1 = x[i * 3 + 1], x2 = x[i * 3 + 2];
        float t0 = x0 * w00 + x1 * w10 + x2 * w20 + agg[i * 3 + 0];
        float t1 = x0 * w01 + x1 * w11 + x2 * w21 + agg[i * 3 + 1];
        float t2 = x0 * w02 + x1 * w12 + x2 * w22 + agg[i * 3 + 2];
        h0 = t0 > 0.0f ? t0 : 0.0f; h1 = t1 > 0.0f ? t1 : 0.0f; h2 = t2 > 0.0f ? t2 : 0.0f;
    }
    #pragma unroll
    for (int off = 32; off > 0; off >>= 1) {
        h0 += __shfl_down(h0, off); h1 += __shfl_down(h1, off); h2 += __shfl_down(h2, off);
    }
    int lane = threadIdx.x & 63, wave = threadIdx.x >> 6;
    if (lane == 0) { part[wave][0] = h0; part[wave][1] = h1; part[wave][2] = h2; }
    __syncthreads();
    if (threadIdx.x == 0) {
        double d0 = 0.0, d1 = 0.0, d2 = 0.0;
        #pragma unroll
        for (int w = 0; w < 4; ++w) {
            d0 += (double)part[w][0]; d1 += (double)part[w][1]; d2 += (double)part[w][2];
        }
        atomicAdd(&sums[0], d0); atomicAdd(&sums[1], d1); atomicAdd(&sums[2], d2);
    }
}

// =====================================================================

extern "C" void kernel_launch(void* const* d_in, const int* in_sizes, int n_in,
                              void* d_out, int out_size, void* d_ws, size_t ws_size,
                              hipStream_t stream) {
    const float* x        = (const float*)d_in[0];
    const float* W        = (const float*)d_in[1];
    const float* M        = (const float*)d_in[2];
    const int*   edge_src = (const int*)d_in[3];
    const int*   edge_dst = (const int*)d_in[4];
    float* out = (float*)d_out;

    char* ws = (char*)d_ws;
    const int nodeBlocks = (N_NODES + 255) / 256;

    if (ws_size >= WS_NEEDED) {
        ushort4*      xmp        = (ushort4*)(ws + XMP_OFF);
        double*       sums       = (double*)(ws + SUMS_OFF);
        int*          bucketFill = (int*)(ws + FILL_OFF);
        unsigned int* records    = (unsigned int*)(ws + REC_OFF);

        prep_kernel<<<nodeBlocks, 256, 0, stream>>>(x, M, xmp, bucketFill, sums);
        bin_kernel<<<BLOCKS_A, 512, 0, stream>>>(edge_src, edge_dst, bucketFill, records);
        bucket_kernel<<<NB, 1024, 0, stream>>>(records, bucketFill, xmp, x, W, sums);
        softmax_kernel<<<1, 1, 0, stream>>>(sums, out);
    } else {
        float*  xm   = (float*)ws;
        float*  agg  = xm + (size_t)N_NODES * 3;
        double* sums = (double*)(agg + (size_t)N_NODES * 3);

        fb_precompute<<<nodeBlocks, 256, 0, stream>>>(x, M, xm, agg, sums);
        fb_scatter<<<2048, 256, 0, stream>>>(edge_src, edge_dst, xm, agg);
        fb_reduce<<<nodeBlocks, 256, 0, stream>>>(x, W, agg, sums);
        softmax_kernel<<<1, 1, 0, stream>>>(sums, out);
    }
}

// Round 14
// 342.549 us; speedup vs baseline: 1.4066x; 1.0164x over previous
//
#include <hip/hip_runtime.h>
#include <hip/hip_fp16.h>

static constexpr int N_NODES = 500000;
static constexpr int N_EDGES = 16000000;

typedef int  iv4 __attribute__((ext_vector_type(4)));
typedef unsigned int uv4 __attribute__((ext_vector_type(4)));

// ---------- fast-path geometry (R5/R13 proven) ----------
static constexpr int BUCKET_SHIFT = 9;                 // 512 nodes / bucket
static constexpr int BUCKET_NODES = 1 << BUCKET_SHIFT; // 512
static constexpr int NB = (N_NODES + BUCKET_NODES - 1) >> BUCKET_SHIFT; // 977
static constexpr int NBUCK = 1024;                     // padded pow2 for LDS arrays
static constexpr int CAP = 18432;                      // per-bucket capacity (mean 16378)
static constexpr int CHUNK = 10000;                    // edges per bin-block (staged = 40 KB)
static constexpr int BLOCKS_A = N_EDGES / CHUNK;       // 1600

// ws layout (bytes) — identical to R5/R13 (proven)
static constexpr size_t XMP_OFF  = 0;                          // ushort4[N_NODES] = 4,000,000
static constexpr size_t SUMS_OFF = 4000000;                    // double[4]
static constexpr size_t FILL_OFF = 4000064;                    // int[1024]
static constexpr size_t REC_OFF  = 4194304;                    // u32[NB*CAP] = 72,030,208
static constexpr size_t WS_NEEDED = REC_OFF + (size_t)NB * CAP * 4;  // 76,224,512

// LDS packed-f16 atomic add: ds_pk_add_f16 (gfx90a+, CDNA4) — proven R13
__device__ __forceinline__ void lds_pk_add_f16(unsigned int* gptr, unsigned int val) {
    unsigned addr = (unsigned)(size_t)(__attribute__((address_space(3))) unsigned int*)gptr;
    asm volatile("ds_pk_add_f16 %0, %1" :: "v"(addr), "v"(val) : "memory");
}

// =====================================================================
// FAST PATH
// =====================================================================

// xm(f16x4) = x @ M ; zero bucketFill and sums
__global__ void prep_kernel(const float* __restrict__ x,
                            const float* __restrict__ M,
                            ushort4* __restrict__ xmp,
                            int* __restrict__ bucketFill,
                            double* __restrict__ sums) {
    int i = blockIdx.x * blockDim.x + threadIdx.x;
    if (i < NBUCK) bucketFill[i] = 0;
    if (i == 0) { sums[0] = 0.0; sums[1] = 0.0; sums[2] = 0.0; }
    if (i < N_NODES) {
        float m00 = M[0], m01 = M[1], m02 = M[2];
        float m10 = M[3], m11 = M[4], m12 = M[5];
        float m20 = M[6], m21 = M[7], m22 = M[8];
        float x0 = x[i * 3 + 0], x1 = x[i * 3 + 1], x2 = x[i * 3 + 2];
        float v0 = x0 * m00 + x1 * m10 + x2 * m20;
        float v1 = x0 * m01 + x1 * m11 + x2 * m21;
        float v2 = x0 * m02 + x1 * m12 + x2 * m22;
        ushort4 u;
        u.x = __half_as_ushort(__float2half_rn(v0));
        u.y = __half_as_ushort(__float2half_rn(v1));
        u.z = __half_as_ushort(__float2half_rn(v2));
        u.w = 0;
        xmp[i] = u;
    }
}

// Partition edges into buckets of 512 dst nodes. 512 threads.
// R14 delta: pass-3 uses 16-lane groups (4 buckets/wave) — runs avg ~10,
// so 64-lane-per-bucket left 85% lanes idle.
__global__ __launch_bounds__(512) void bin_kernel(const int* __restrict__ edge_src,
                                                  const int* __restrict__ edge_dst,
                                                  int* __restrict__ bucketFill,
                                                  unsigned int* __restrict__ records) {
    __shared__ int cnt[NBUCK];                 // 4 KB: histogram, then cursor
    __shared__ unsigned short start[NBUCK];    // 2 KB
    __shared__ unsigned short gbase[NBUCK];    // 2 KB
    __shared__ int part[256];                  // 1 KB
    __shared__ unsigned int staged[CHUNK];     // 40 KB

    const int t = threadIdx.x;
    const long e0 = (long)blockIdx.x * CHUNK;
    const iv4* __restrict__ dst4 = reinterpret_cast<const iv4*>(edge_dst + e0);
    const iv4* __restrict__ src4 = reinterpret_cast<const iv4*>(edge_src + e0);

    for (int b = t; b < NBUCK; b += 512) cnt[b] = 0;
    __syncthreads();

    // pass 1: histogram of dst buckets (nt int4 loads)
    for (int i = t; i < CHUNK / 4; i += 512) {
        iv4 d = __builtin_nontemporal_load(dst4 + i);
        atomicAdd(&cnt[d.x >> BUCKET_SHIFT], 1);
        atomicAdd(&cnt[d.y >> BUCKET_SHIFT], 1);
        atomicAdd(&cnt[d.z >> BUCKET_SHIFT], 1);
        atomicAdd(&cnt[d.w >> BUCKET_SHIFT], 1);
    }
    __syncthreads();

    // exclusive scan of cnt[0..1023] -> start[] (threads 0..255 drive)
    int a0 = 0, a1 = 0, a2 = 0, a3 = 0, tsum = 0;
    if (t < 256) {
        a0 = cnt[4 * t + 0]; a1 = cnt[4 * t + 1]; a2 = cnt[4 * t + 2]; a3 = cnt[4 * t + 3];
        tsum = a0 + a1 + a2 + a3;
        part[t] = tsum;
    }
    __syncthreads();
    for (int off = 1; off < 256; off <<= 1) {
        int u = 0, v = 0;
        if (t < 256) { u = part[t]; v = (t >= off) ? part[t - off] : 0; }
        __syncthreads();
        if (t < 256) part[t] = u + v;
        __syncthreads();
    }
    if (t < 256) {
        int texcl = part[t] - tsum;
        start[4 * t + 0] = (unsigned short)texcl;
        start[4 * t + 1] = (unsigned short)(texcl + a0);
        start[4 * t + 2] = (unsigned short)(texcl + a0 + a1);
        start[4 * t + 3] = (unsigned short)(texcl + a0 + a1 + a2);
    }
    __syncthreads();

    // global reservation (rotated); then cursor = start
    for (int j = t; j < NBUCK; j += 512) {
        int b = (j + blockIdx.x * 7) & (NBUCK - 1);
        int c = cnt[b];
        gbase[b] = (unsigned short)((c > 0) ? atomicAdd(&bucketFill[b], c) : 0);
    }
    __syncthreads();
    for (int b = t; b < NBUCK; b += 512) cnt[b] = (int)start[b];
    __syncthreads();

    // pass 2: stage records grouped by bucket
    for (int i = t; i < CHUNK / 4; i += 512) {
        iv4 d = __builtin_nontemporal_load(dst4 + i);
        iv4 s = __builtin_nontemporal_load(src4 + i);
        int dd[4] = { d.x, d.y, d.z, d.w };
        int ss[4] = { s.x, s.y, s.z, s.w };
        #pragma unroll
        for (int k = 0; k < 4; ++k) {
            int b = dd[k] >> BUCKET_SHIFT;
            int r = atomicAdd(&cnt[b], 1);
            staged[r] = ((unsigned int)(dd[k] & (BUCKET_NODES - 1)) << 20) | (unsigned int)ss[k];
        }
    }
    __syncthreads();

    // pass 3: 16-lane-group-per-bucket copy (32 buckets in flight)
    const int wv = t >> 6, ln = t & 63;
    const int grp = ln >> 4, q = ln & 15;
    for (int b = wv * 4 + grp; b < NBUCK; b += 32) {
        int s0 = (int)start[b];
        int c  = cnt[b] - s0;
        int g  = (int)gbase[b];
        for (int i = q; i < c; i += 16) {
            int pos = g + i;
            if (pos < CAP)
                __builtin_nontemporal_store(staged[s0 + i], &records[(size_t)b * CAP + pos]);
        }
    }
}

// per-record accumulate: 1 ds_pk_add_f16 (v0,v1) + 1 ds_add_f32 (v2)
#define DO_REC(AGGH, AGGV, RW, GV)                                                   \
    {                                                                                \
        int dl_ = (int)((RW) >> 20);                                                 \
        lds_pk_add_f16(&(AGGH)[dl_], (unsigned int)((GV) & 0xFFFFFFFFull));          \
        float v2_ = __half2float(__ushort_as_half((unsigned short)(((GV) >> 32) & 0xFFFF))); \
        atomicAdd(&(AGGV)[dl_], v2_);                                                \
    }

// One block (1024 thr) per bucket. R14 delta vs R13: 2-stage software
// pipeline — batch i+1's record load + gathers issue BEFORE batch i's
// atomics, overlapping L2 gather latency with LDS atomic time.
__global__ __launch_bounds__(1024) void bucket_kernel(const unsigned int* __restrict__ records,
                                                      const int* __restrict__ bucketFill,
                                                      const ushort4* __restrict__ xmp,
                                                      const float* __restrict__ x,
                                                      const float* __restrict__ W,
                                                      double* __restrict__ sums) {
    __shared__ unsigned int aggH2[BUCKET_NODES];  // 2 KB: packed f16 (v0,v1)
    __shared__ float        aggV2[BUCKET_NODES];  // 2 KB: v2 (f32)
    __shared__ float        partw[16][3];

    const int b = blockIdx.x;
    const int t = threadIdx.x;
    const unsigned long long* __restrict__ xmp8 = (const unsigned long long*)xmp;

    for (int i = t; i < BUCKET_NODES; i += 1024) {
        aggH2[i] = 0u;
        aggV2[i] = 0.0f;
    }
    __syncthreads();

    int cnt = bucketFill[b];
    if (cnt > CAP) cnt = CAP;
    const unsigned int* __restrict__ rec = records + (size_t)b * CAP;
    const uv4* __restrict__ rec4 = reinterpret_cast<const uv4*>(rec);
    const int nb = cnt >> 2;

    // ---- 2-stage modulo-scheduled pipeline over uint4 batches ----
    int i = t;
    uv4 rA = {};
    unsigned long long gA0 = 0, gA1 = 0, gA2 = 0, gA3 = 0;
    bool vA = (i < nb);
    if (vA) {
        rA = __builtin_nontemporal_load(rec4 + i);
        gA0 = xmp8[rA.x & 0xFFFFFu];
        gA1 = xmp8[rA.y & 0xFFFFFu];
        gA2 = xmp8[rA.z & 0xFFFFFu];
        gA3 = xmp8[rA.w & 0xFFFFFu];
    }
    while (vA) {
        int j = i + 1024;
        uv4 rB = {};
        unsigned long long gB0 = 0, gB1 = 0, gB2 = 0, gB3 = 0;
        bool vB = (j < nb);
        if (vB) {
            rB = __builtin_nontemporal_load(rec4 + j);
            gB0 = xmp8[rB.x & 0xFFFFFu];
            gB1 = xmp8[rB.y & 0xFFFFFu];
            gB2 = xmp8[rB.z & 0xFFFFFu];
            gB3 = xmp8[rB.w & 0xFFFFFu];
        }
        __builtin_amdgcn_sched_barrier(0);   // keep B-prefetch above A-atomics
        DO_REC(aggH2, aggV2, rA.x, gA0);
        DO_REC(aggH2, aggV2, rA.y, gA1);
        DO_REC(aggH2, aggV2, rA.z, gA2);
        DO_REC(aggH2, aggV2, rA.w, gA3);
        if (!vB) break;
        i = j + 1024;
        vA = (i < nb);
        if (vA) {
            rA = __builtin_nontemporal_load(rec4 + i);
            gA0 = xmp8[rA.x & 0xFFFFFu];
            gA1 = xmp8[rA.y & 0xFFFFFu];
            gA2 = xmp8[rA.z & 0xFFFFFu];
            gA3 = xmp8[rA.w & 0xFFFFFu];
        }
        __builtin_amdgcn_sched_barrier(0);   // keep A'-prefetch above B-atomics
        DO_REC(aggH2, aggV2, rB.x, gB0);
        DO_REC(aggH2, aggV2, rB.y, gB1);
        DO_REC(aggH2, aggV2, rB.z, gB2);
        DO_REC(aggH2, aggV2, rB.w, gB3);
    }

    // scalar tail (cnt & 3 records)
    for (int it = (nb << 2) + t; it < cnt; it += 1024) {
        unsigned int r = rec[it];
        unsigned long long g = xmp8[r & 0xFFFFFu];
        DO_REC(aggH2, aggV2, r, g);
    }
    __syncthreads();

    // fused epilogue: h = relu(x@W + agg), block partial sum (one node per thread t<512)
    float s0 = 0.0f, s1 = 0.0f, s2 = 0.0f;
    if (t < BUCKET_NODES) {
        int node = (b << BUCKET_SHIFT) + t;
        if (node < N_NODES) {
            float w00 = W[0], w01 = W[1], w02 = W[2];
            float w10 = W[3], w11 = W[4], w12 = W[5];
            float w20 = W[6], w21 = W[7], w22 = W[8];
            float x0 = x[node * 3 + 0], x1 = x[node * 3 + 1], x2 = x[node * 3 + 2];
            unsigned int u = aggH2[t];
            float a0 = __half2float(__ushort_as_half((unsigned short)(u & 0xFFFF)));
            float a1 = __half2float(__ushort_as_half((unsigned short)(u >> 16)));
            float a2f = aggV2[t];
            float t0 = x0 * w00 + x1 * w10 + x2 * w20 + a0;
            float t1 = x0 * w01 + x1 * w11 + x2 * w21 + a1;
            float t2 = x0 * w02 + x1 * w12 + x2 * w22 + a2f;
            s0 = t0 > 0.0f ? t0 : 0.0f;
            s1 = t1 > 0.0f ? t1 : 0.0f;
            s2 = t2 > 0.0f ? t2 : 0.0f;
        }
    }

    #pragma unroll
    for (int off = 32; off > 0; off >>= 1) {
        s0 += __shfl_down(s0, off);
        s1 += __shfl_down(s1, off);
        s2 += __shfl_down(s2, off);
    }
    int lane = t & 63, wave = t >> 6;
    if (lane == 0) { partw[wave][0] = s0; partw[wave][1] = s1; partw[wave][2] = s2; }
    __syncthreads();
    if (t == 0) {
        double d0 = 0.0, d1 = 0.0, d2 = 0.0;
        #pragma unroll
        for (int w = 0; w < 16; ++w) {
            d0 += (double)partw[w][0];
            d1 += (double)partw[w][1];
            d2 += (double)partw[w][2];
        }
        atomicAdd(&sums[0], d0);
        atomicAdd(&sums[1], d1);
        atomicAdd(&sums[2], d2);
    }
}

__global__ void softmax_kernel(const double* __restrict__ sums,
                               float* __restrict__ out) {
    if (blockIdx.x == 0 && threadIdx.x == 0) {
        double s0 = sums[0], s1 = sums[1], s2 = sums[2];
        double m = fmax(s0, fmax(s1, s2));
        double e0 = exp(s0 - m), e1 = exp(s1 - m), e2 = exp(s2 - m);
        double tt = e0 + e1 + e2;
        out[0] = (float)(e0 / tt);
        out[1] = (float)(e1 / tt);
        out[2] = (float)(e2 / tt);
    }
}

// =====================================================================
// FALLBACK PATH (proven R1 code) — used if ws_size < WS_NEEDED
// =====================================================================

__global__ void fb_precompute(const float* __restrict__ x, const float* __restrict__ M,
                              float* __restrict__ xm, float* __restrict__ agg,
                              double* __restrict__ sums) {
    int i = blockIdx.x * blockDim.x + threadIdx.x;
    if (i == 0) { sums[0] = 0.0; sums[1] = 0.0; sums[2] = 0.0; }
    if (i < N_NODES) {
        float m00 = M[0], m01 = M[1], m02 = M[2];
        float m10 = M[3], m11 = M[4], m12 = M[5];
        float m20 = M[6], m21 = M[7], m22 = M[8];
        float x0 = x[i * 3 + 0], x1 = x[i * 3 + 1], x2 = x[i * 3 + 2];
        xm[i * 3 + 0] = x0 * m00 + x1 * m10 + x2 * m20;
        xm[i * 3 + 1] = x0 * m01 + x1 * m11 + x2 * m21;
        xm[i * 3 + 2] = x0 * m02 + x1 * m12 + x2 * m22;
        agg[i * 3 + 0] = 0.0f; agg[i * 3 + 1] = 0.0f; agg[i * 3 + 2] = 0.0f;
    }
}

__global__ void fb_scatter(const int* __restrict__ edge_src, const int* __restrict__ edge_dst,
                           const float* __restrict__ xm, float* __restrict__ agg) {
    const int tid = blockIdx.x * blockDim.x + threadIdx.x;
    const int stride = gridDim.x * blockDim.x;
    const int4* src4 = reinterpret_cast<const int4*>(edge_src);
    const int4* dst4 = reinterpret_cast<const int4*>(edge_dst);
    const int n4 = N_EDGES / 4;
    for (int e = tid; e < n4; e += stride) {
        int4 s = src4[e]; int4 d = dst4[e];
        int ss[4] = { s.x, s.y, s.z, s.w };
        int dd[4] = { d.x, d.y, d.z, d.w };
        float v[4][3];
        #pragma unroll
        for (int k = 0; k < 4; ++k) {
            int bb = ss[k] * 3;
            v[k][0] = xm[bb + 0]; v[k][1] = xm[bb + 1]; v[k][2] = xm[bb + 2];
        }
        #pragma unroll
        for (int k = 0; k < 4; ++k) {
            int bb = dd[k] * 3;
            atomicAdd(&agg[bb + 0], v[k][0]);
            atomicAdd(&agg[bb + 1], v[k][1]);
            atomicAdd(&agg[bb + 2], v[k][2]);
        }
    }
}

__global__ void fb_reduce(const float* __restrict__ x, const float* __restrict__ W,
                          const float* __restrict__ agg, double* __restrict__ sums) {
    __shared__ float part[4][3];
    int i = blockIdx.x * blockDim.x + threadIdx.x;
    float h0 = 0.0f, h1 = 0.0f, h2 = 0.0f;
    if (i < N_NODES) {
        float w00 = W[0], w01 = W[1], w02 = W[2];
        float w10 = W[3], w11 = W[4], w12 = W[5];
        float w20 = W[6], w21 = W[7], w22 = W[8];
        float x0 = x[i * 3 + 0], x1 = x[i * 3 + 1], x2 = x[i * 3 + 2];
        float t0 = x0 * w00 + x1 * w10 + x2 * w20 + agg[i * 3 + 0];
        float t1 = x0 * w01 + x1 * w11 + x2 * w21 + agg[i * 3 + 1];
        float t2 = x0 * w02 + x1 * w12 + x2 * w22 + agg[i * 3 + 2];
        h0 = t0 > 0.0f ? t0 : 0.0f; h1 = t1 > 0.0f ? t1 : 0.0f; h2 = t2 > 0.0f ? t2 : 0.0f;
    }
    #pragma unroll
    for (int off = 32; off > 0; off >>= 1) {
        h0 += __shfl_down(h0, off); h1 += __shfl_down(h1, off); h2 += __shfl_down(h2, off);
    }
    int lane = threadIdx.x & 63, wave = threadIdx.x >> 6;
    if (lane == 0) { part[wave][0] = h0; part[wave][1] = h1; part[wave][2] = h2; }
    __syncthreads();
    if (threadIdx.x == 0) {
        double d0 = 0.0, d1 = 0.0, d2 = 0.0;
        #pragma unroll
        for (int w = 0; w < 4; ++w) {
            d0 += (double)part[w][0]; d1 += (double)part[w][1]; d2 += (double)part[w][2];
        }
        atomicAdd(&sums[0], d0); atomicAdd(&sums[1], d1); atomicAdd(&sums[2], d2);
    }
}

// =====================================================================

extern "C" void kernel_launch(void* const* d_in, const int* in_sizes, int n_in,
                              void* d_out, int out_size, void* d_ws, size_t ws_size,
                              hipStream_t stream) {
    const float* x        = (const float*)d_in[0];
    const float* W        = (const float*)d_in[1];
    const float* M        = (const float*)d_in[2];
    const int*   edge_src = (const int*)d_in[3];
    const int*   edge_dst = (const int*)d_in[4];
    float* out = (float*)d_out;

    char* ws = (char*)d_ws;
    const int nodeBlocks = (N_NODES + 255) / 256;

    if (ws_size >= WS_NEEDED) {
        ushort4*      xmp        = (ushort4*)(ws + XMP_OFF);
        double*       sums       = (double*)(ws + SUMS_OFF);
        int*          bucketFill = (int*)(ws + FILL_OFF);
        unsigned int* records    = (unsigned int*)(ws + REC_OFF);

        prep_kernel<<<nodeBlocks, 256, 0, stream>>>(x, M, xmp, bucketFill, sums);
        bin_kernel<<<BLOCKS_A, 512, 0, stream>>>(edge_src, edge_dst, bucketFill, records);
        bucket_kernel<<<NB, 1024, 0, stream>>>(records, bucketFill, xmp, x, W, sums);
        softmax_kernel<<<1, 1, 0, stream>>>(sums, out);
    } else {
        float*  xm   = (float*)ws;
        float*  agg  = xm + (size_t)N_NODES * 3;
        double* sums = (double*)(agg + (size_t)N_NODES * 3);

        fb_precompute<<<nodeBlocks, 256, 0, stream>>>(x, M, xm, agg, sums);
        fb_scatter<<<2048, 256, 0, stream>>>(edge_src, edge_dst, xm, agg);
        fb_reduce<<<nodeBlocks, 256, 0, stream>>>(x, W, agg, sums);
        softmax_kernel<<<1, 1, 0, stream>>>(sums, out);
    }
}